// Round 14
// baseline (330.949 us; speedup 1.0000x reference)
//
#include <hip/hip_runtime.h>
#include <stdint.h>

// ---------------------------------------------------------------------------
// GC_FFM fusion block on MI355X (gfx950), bf16 MFMA pipeline.
// N=2, C=256, RC=32, H=W=64, HW=4096.
// R20: final prefetch-depth polish (pattern proven R13/R19):
//  a) conv3: A-tap rotation deepened to 3-ahead (4 sets, VGPR ~112 < 128).
//  b) gemm_k: A-operand 1-chunk-ahead prefetch (was loaded at use, ~200cy
//     exposed per chunk under barrier-coupled waves).
//  c) proj_k both roles: same A prefetch.
// R19 lesson: conv3 latency theory confirmed (83.2->79.5, MfmaUtil 18->19).
// R18 lesson: R16 state reproducible; pad-74 falsified by counters.
// R17 lesson: 64m/wave at 1 blk/CU collapses occupancy (82->102us).
// R16 lesson: producer-consumer attn3 88 -> <80us. Sweet spots bracketed.
// R12 lesson: thin iterations regress; R13: attn3 barrier-bound.
// R11 lesson: XCD pin + LDS-only barrier + Z-fusion + setprio proven.
// R8  lesson: __syncthreads drains vmcnt(0) -> never in a hot loop.
// ---------------------------------------------------------------------------

typedef __bf16 bf16_t;
typedef __bf16 bf16x8 __attribute__((ext_vector_type(8)));
typedef float f32x4 __attribute__((ext_vector_type(4)));

#define HW 4096
#define NB 2

__device__ inline f32x4 mfma_bf16(bf16x8 a, bf16x8 b, f32x4 c) {
    return __builtin_amdgcn_mfma_f32_16x16x32_bf16(a, b, c, 0, 0, 0);
}

// LDS-only barrier: drain LDS ops, sync, pin schedule. Global loads stay
// in flight across it (R11-proven race-free for write->read->overwrite).
#define LBAR()                                                                 \
    do {                                                                       \
        asm volatile("s_waitcnt lgkmcnt(0)" ::: "memory");                     \
        __builtin_amdgcn_s_barrier();                                          \
        __builtin_amdgcn_sched_barrier(0);                                     \
    } while (0)

// ---------------------------------------------------------------------------
// prep_k: batched fp32->bf16 convert + fus2 reorder + bias pack, one launch.
// ---------------------------------------------------------------------------
#define MAXJOB 12
struct CvtJobs {
    const float* src[MAXJOB];
    bf16_t* dst[MAXJOB];
    int vend[MAXJOB];     // cumulative end, vec8 units
    int rowlen[MAXJOB];
    int rowstride[MAXJOB];
    int rowoff[MAXJOB];
};

__global__ __launch_bounds__(256) void prep_k(CvtJobs J, int totalvec, int cvtBlocks,
                                              const float* __restrict__ fus2_src,
                                              bf16_t* __restrict__ fus2_dst,
                                              const float* qr, const float* kr,
                                              const float* qd, const float* kd,
                                              const float* sb, const float* fb,
                                              float* BQK_R, float* BQK_D, float* BSUM) {
    const int b = blockIdx.x, t = threadIdx.x;
    if (b < cvtBlocks) {
        int gv = b * 256 + t;
        if (gv >= totalvec) return;
        int j = 0;
        while (gv >= J.vend[j]) j++;
        int vbase = (j == 0) ? 0 : J.vend[j - 1];
        int e = (gv - vbase) * 8;
        const float* s = J.src[j] + e;
        float4 f0 = *(const float4*)s;
        float4 f1 = *(const float4*)(s + 4);
        bf16x8 o;
        o[0] = (bf16_t)f0.x; o[1] = (bf16_t)f0.y; o[2] = (bf16_t)f0.z; o[3] = (bf16_t)f0.w;
        o[4] = (bf16_t)f1.x; o[5] = (bf16_t)f1.y; o[6] = (bf16_t)f1.z; o[7] = (bf16_t)f1.w;
        int di = e;
        if (J.rowlen[j])
            di = (e / J.rowlen[j]) * J.rowstride[j] + J.rowoff[j] + (e % J.rowlen[j]);
        *(bf16x8*)(J.dst[j] + di) = o;
    } else if (b < cvtBlocks + 9216) {
        // fus2_w [O=512][C=512][3][3] -> A'[o][ (dy*3+dx)*512 + c ]
        int idx = (b - cvtBlocks) * 256 + t;
        int o = idx / 4608;
        int tt = idx % 4608;
        int t9 = tt / 512;
        int c  = tt % 512;
        fus2_dst[idx] = (bf16_t)fus2_src[(size_t)o * 4608 + c * 9 + t9];
    } else {
        if (t < 32) {
            BQK_R[t] = qr[t]; BQK_R[32 + t] = kr[t];
            BQK_D[t] = qd[t]; BQK_D[32 + t] = kd[t];
        }
        BSUM[t] = sb[t] + fb[t];
    }
}

// ---------------------------------------------------------------------------
// proj_k: V-proj (blocks 0..511) + QKT (blocks 512..639), 512 threads.
// R20: A-operand 1-chunk-ahead prefetch in both roles.
// ---------------------------------------------------------------------------
__global__ __launch_bounds__(512) void proj_k(const bf16_t* __restrict__ WV_R,
                                              const bf16_t* __restrict__ WV_D,
                                              const bf16_t* __restrict__ WQK_R,
                                              const bf16_t* __restrict__ WQK_D,
                                              const bf16_t* __restrict__ XB,
                                              const float* __restrict__ vb_r,
                                              const float* __restrict__ vb_d,
                                              const float* __restrict__ bqk_r,
                                              const float* __restrict__ bqk_d,
                                              bf16_t* __restrict__ V4,
                                              bf16_t* __restrict__ QKT) {
    __shared__ bf16_t Bt[2][64][72];
    const int t = threadIdx.x, b = blockIdx.x;
    const int w = t >> 6, lane = t & 63, quad = lane >> 4, l16 = lane & 15;

    f32x4 zero = {0.f, 0.f, 0.f, 0.f};
    f32x4 acc[4] = {zero, zero, zero, zero};

    if (b < 512) {
        // ---- V-proj role (NW8) --------------------------------------------
        const int mb = b & 1, jb = (b >> 1) & 63, n = b >> 7;
        const bf16_t* Au = (n >= 2) ? WV_D : WV_R;
        const float* biasu = (n >= 2) ? vb_d : vb_r;
        const bf16_t* Bb = XB + (size_t)n * (256 * HW) + jb * 64;
        const bf16_t* Arow = Au + (size_t)(mb * 128 + w * 16 + l16) * 256 + quad * 8;

        bf16x8 v0 = *(const bf16x8*)(Bb + (size_t)lane * HW + w * 8);
        bf16x8 a0 = *(const bf16x8*)(Arow);
        bf16x8 a1 = *(const bf16x8*)(Arow + 32);
        for (int k0 = 0; k0 < 256; k0 += 64) {
            LBAR();  // prev readers done
#pragma unroll
            for (int e = 0; e < 8; e++) Bt[0][w * 8 + e][lane] = v0[e];
            LBAR();  // tile ready
            const int kn = (k0 + 64 < 256) ? k0 + 64 : 0;
            bf16x8 vp = *(const bf16x8*)(Bb + (size_t)(kn + lane) * HW + w * 8);
            bf16x8 a0n = *(const bf16x8*)(Arow + kn);
            bf16x8 a1n = *(const bf16x8*)(Arow + kn + 32);
#pragma unroll
            for (int ns = 0; ns < 4; ns++) {
                bf16x8 b0 = *(const bf16x8*)&Bt[0][ns * 16 + l16][quad * 8];
                bf16x8 b1 = *(const bf16x8*)&Bt[0][ns * 16 + l16][32 + quad * 8];
                acc[ns] = mfma_bf16(a0, b0, acc[ns]);
                acc[ns] = mfma_bf16(a1, b1, acc[ns]);
            }
            v0 = vp; a0 = a0n; a1 = a1n;
        }
#pragma unroll
        for (int ns = 0; ns < 4; ns++) {
#pragma unroll
            for (int rr = 0; rr < 4; rr++) {
                int m = mb * 128 + w * 16 + quad * 4 + rr;
                int col = jb * 64 + ns * 16 + l16;
                V4[(size_t)n * 256 * HW + (size_t)m * HW + col] =
                    (bf16_t)(acc[ns][rr] + biasu[m]);
            }
        }
    } else {
        // ---- QKT role: two 4-wave groups ----------------------------------
        const int qb = b - 512;                  // 0..127
        const int n2 = qb >> 5, jpair = qb & 31;
        const int g = w >> 2, wg = w & 3;
        const int jb = jpair * 2 + g;
        const bf16_t* Au = (n2 >= 2) ? WQK_D : WQK_R;
        const float* biasu = (n2 >= 2) ? bqk_d : bqk_r;
        const bf16_t* Bb = XB + (size_t)n2 * (256 * HW) + jb * 64;
        const bf16_t* Arow = Au + (size_t)(wg * 16 + l16) * 256 + quad * 8;

        bf16x8 v0 = *(const bf16x8*)(Bb + (size_t)lane * HW + wg * 16);
        bf16x8 v1 = *(const bf16x8*)(Bb + (size_t)lane * HW + wg * 16 + 8);
        bf16x8 a0 = *(const bf16x8*)(Arow);
        bf16x8 a1 = *(const bf16x8*)(Arow + 32);
        for (int k0 = 0; k0 < 256; k0 += 64) {
            LBAR();  // prev readers done
#pragma unroll
            for (int e = 0; e < 8; e++) Bt[g][wg * 16 + e][lane] = v0[e];
#pragma unroll
            for (int e = 0; e < 8; e++) Bt[g][wg * 16 + 8 + e][lane] = v1[e];
            LBAR();  // tile ready
            const int kn = (k0 + 64 < 256) ? k0 + 64 : 0;
            bf16x8 p0 = *(const bf16x8*)(Bb + (size_t)(kn + lane) * HW + wg * 16);
            bf16x8 p1 = *(const bf16x8*)(Bb + (size_t)(kn + lane) * HW + wg * 16 + 8);
            bf16x8 a0n = *(const bf16x8*)(Arow + kn);
            bf16x8 a1n = *(const bf16x8*)(Arow + kn + 32);
#pragma unroll
            for (int ns = 0; ns < 4; ns++) {
                bf16x8 b0 = *(const bf16x8*)&Bt[g][ns * 16 + l16][quad * 8];
                bf16x8 b1 = *(const bf16x8*)&Bt[g][ns * 16 + l16][32 + quad * 8];
                acc[ns] = mfma_bf16(a0, b0, acc[ns]);
                acc[ns] = mfma_bf16(a1, b1, acc[ns]);
            }
            v0 = p0; v1 = p1; a0 = a0n; a1 = a1n;
        }
        // EPI6: transposed store, q-rows (wg<2) pre-scaled by log2e
        const float scl = (wg < 2) ? 1.44269504f : 1.0f;
#pragma unroll
        for (int ns = 0; ns < 4; ns++) {
            int col = jb * 64 + ns * 16 + l16;
            union { bf16_t h[4]; unsigned long long u; } pk;
#pragma unroll
            for (int rr = 0; rr < 4; rr++) {
                int m = wg * 16 + quad * 4 + rr;
                pk.h[rr] = (bf16_t)((acc[ns][rr] + biasu[m]) * scl);
            }
            *(unsigned long long*)(QKT +
                ((size_t)n2 * HW + col) * 64 + wg * 16 + quad * 4) = pk.u;
        }
    }
}

// ---------------------------------------------------------------------------
// Generic bf16 GEMM (NW=8): out = epi( A[z] . B[z] + bias ), dual-A.
// LDS-only barriers + 1-chunk-ahead B AND A prefetch (R20).
// EPI: 0 none (fp32 or bf16), 5 gate-fuse, 7 NHWC transposed relu store.
// ---------------------------------------------------------------------------
template <int EPI, bool OUT_BF16>
__global__ __launch_bounds__(512) void gemm_k(const bf16_t* __restrict__ A,
                                              const bf16_t* __restrict__ A2,
                                              const bf16_t* __restrict__ B,
                                              const float* __restrict__ bias,
                                              const float* __restrict__ bias2,
                                              void* __restrict__ outp,
                                              const void* __restrict__ aux,
                                              int M, int K, size_t strideB, size_t strideO) {
    __shared__ bf16_t Bt[64][72];
    const int t = threadIdx.x;
    const int mb = blockIdx.x, jb = blockIdx.y, n = blockIdx.z;
    const int w = t >> 6, lane = t & 63, quad = lane >> 4, l16 = lane & 15;

    const bf16_t* Au = (n >= 2) ? A2 : A;
    const float* biasu = (n >= 2) ? bias2 : bias;

    const bf16_t* Bb = B + (size_t)n * strideB + jb * 64;

    f32x4 zero = {0.f, 0.f, 0.f, 0.f};
    f32x4 acc[4] = {zero, zero, zero, zero};

    const bf16_t* Arow = Au + (size_t)(mb * 128 + w * 16 + l16) * K + quad * 8;

    bf16x8 v0 = *(const bf16x8*)(Bb + (size_t)lane * HW + w * 8);
    bf16x8 a0 = *(const bf16x8*)(Arow);
    bf16x8 a1 = *(const bf16x8*)(Arow + 32);
    for (int k0 = 0; k0 < K; k0 += 64) {
        LBAR();  // prev readers done (global loads stay in flight)
#pragma unroll
        for (int e = 0; e < 8; e++) Bt[w * 8 + e][lane] = v0[e];
        LBAR();  // tile ready
        const int kn = (k0 + 64 < K) ? k0 + 64 : 0;
        bf16x8 vp = *(const bf16x8*)(Bb + (size_t)(kn + lane) * HW + w * 8);
        bf16x8 a0n = *(const bf16x8*)(Arow + kn);
        bf16x8 a1n = *(const bf16x8*)(Arow + kn + 32);
#pragma unroll
        for (int ns = 0; ns < 4; ns++) {
            bf16x8 b0 = *(const bf16x8*)&Bt[ns * 16 + l16][quad * 8];
            bf16x8 b1 = *(const bf16x8*)&Bt[ns * 16 + l16][32 + quad * 8];
            acc[ns] = mfma_bf16(a0, b0, acc[ns]);
            acc[ns] = mfma_bf16(a1, b1, acc[ns]);
        }
        v0 = vp; a0 = a0n; a1 = a1n;
    }

    if (EPI == 7) {
        // NHWC transposed relu store: Y1[(n*HW + col)*512 + m_base..+4]
        const int m_base = mb * 128 + w * 16 + quad * 4;
#pragma unroll
        for (int ns = 0; ns < 4; ns++) {
            int col = jb * 64 + ns * 16 + l16;
            union { bf16_t h[4]; unsigned long long u; } pk;
#pragma unroll
            for (int rr = 0; rr < 4; rr++) {
                float v = acc[ns][rr] + biasu[m_base + rr];
                pk.h[rr] = (bf16_t)(v > 0.f ? v : 0.f);
            }
            *(unsigned long long*)((bf16_t*)outp +
                ((size_t)n * HW + col) * 512 + m_base) = pk.u;
        }
    } else if (EPI == 5) {
        const bf16_t* catp = (const bf16_t*)aux;
        bf16_t* f = (bf16_t*)outp;
#pragma unroll
        for (int ns = 0; ns < 4; ns++) {
#pragma unroll
            for (int rr = 0; rr < 4; rr++) {
                int m = mb * 128 + w * 16 + quad * 4 + rr;
                int col = jb * 64 + ns * 16 + l16;
                float v = acc[ns][rr] + biasu[m];
                float g = 1.f / (1.f + __expf(-v));
                size_t base = (size_t)n * 512 * HW + (size_t)m * HW + col;
                float br = (float)catp[base];
                float bd = (float)catp[base + (size_t)256 * HW];
                size_t ob = (size_t)n * 1024 * HW + (size_t)m * HW + col;
                f[ob] = (bf16_t)(br * g + bd * (1.f - g));
                f[ob + (size_t)256 * HW] = (bf16_t)(br * bd);
            }
        }
    } else {
#pragma unroll
        for (int ns = 0; ns < 4; ns++) {
#pragma unroll
            for (int rr = 0; rr < 4; rr++) {
                int m = mb * 128 + w * 16 + quad * 4 + rr;
                int col = jb * 64 + ns * 16 + l16;
                float v = acc[ns][rr] + biasu[m];
                size_t oi = (size_t)n * strideO + (size_t)m * HW + col;
                if (OUT_BF16) ((bf16_t*)outp)[oi] = (bf16_t)v;
                else ((float*)outp)[oi] = v;
            }
        }
    }
}

// ---------------------------------------------------------------------------
// conv3x3 implicit GEMM v7 (R20): R16 structure (32m/wave, grid 512,
// 2 blk/CU) + A-tap prefetch deepened to 3 taps (4-set rotation).
// Prefetch distance ~450cy >= worst-case L2 latency. VGPR ~112 < 128 cliff.
// ---------------------------------------------------------------------------
__global__ __launch_bounds__(256) void conv3_k(const bf16_t* __restrict__ A,
                                               const bf16_t* __restrict__ Y1n,
                                               const float* __restrict__ bias,
                                               bf16_t* __restrict__ outp,
                                               size_t strideN) {
    __shared__ bf16_t kTn[198][72];  // [px_slot][channel], pad 72 (144B rows)
    const int t = threadIdx.x;
    const int lin = blockIdx.x;
    const int n = lin & 1, mb = (lin >> 1) & 3, y = lin >> 3;
    const int w = t >> 6, lane = t & 63, quad = lane >> 4, l16 = lane & 15;

    f32x4 zero = {0.f, 0.f, 0.f, 0.f};
    f32x4 acc[2][4];
#pragma unroll
    for (int i = 0; i < 2; i++)
#pragma unroll
        for (int j = 0; j < 4; j++) acc[i][j] = zero;

    const bf16_t* Yb = Y1n + (size_t)n * HW * 512;

    const bf16_t* Arow[2];
    Arow[0] = A + (size_t)(mb * 128 + w * 32 + l16) * 4608 + quad * 8;
    Arow[1] = Arow[0] + (size_t)16 * 4608;

    // staging slot geometry: 198 px_slots x 8 ch-segments = 1584 16B units
    int pxs[7], seg[7], gidx[7];
    bool ok[7], act[7];
#pragma unroll
    for (int i = 0; i < 7; i++) {
        int slot = t + i * 256;
        act[i] = slot < 1584;
        int ps = act[i] ? (slot >> 3) : 0;
        pxs[i] = ps;
        seg[i] = slot & 7;
        int r = ps / 66, xm = ps % 66;
        int yy = y + r - 1, xx = xm - 1;
        ok[i] = act[i] && ((unsigned)yy < 64u) && ((unsigned)xx < 64u);
        gidx[i] = ok[i] ? (yy * 64 + xx) : 0;
    }

    bf16x8 vals[7];
    // prologue: chunk 0 staged loads
#pragma unroll
    for (int i = 0; i < 7; i++) {
        bf16x8 v;
        if (ok[i]) {
            v = *(const bf16x8*)(Yb + (size_t)gidx[i] * 512 + seg[i] * 8);
        } else {
#pragma unroll
            for (int e = 0; e < 8; e++) v[e] = (bf16_t)0.f;
        }
        vals[i] = v;
    }

    // prologue: A frags for chunk0 taps 0,1,2 (4-set rotation)
    bf16x8 af0[2][2], af1[2][2], af2[2][2], af3[2][2];
#pragma unroll
    for (int h = 0; h < 2; h++) {
        af0[h][0] = *(const bf16x8*)(Arow[h]);
        af0[h][1] = *(const bf16x8*)(Arow[h] + 32);
        af1[h][0] = *(const bf16x8*)(Arow[h] + 512);
        af1[h][1] = *(const bf16x8*)(Arow[h] + 512 + 32);
        af2[h][0] = *(const bf16x8*)(Arow[h] + 1024);
        af2[h][1] = *(const bf16x8*)(Arow[h] + 1024 + 32);
    }

    for (int c0 = 0; c0 < 512; c0 += 64) {
        LBAR();  // prev chunk's readers done (staged loads stay in flight)
#pragma unroll
        for (int i = 0; i < 7; i++)
            if (act[i]) *(bf16x8*)&kTn[pxs[i]][seg[i] * 8] = vals[i];
        LBAR();  // tile ready

        // prefetch next chunk's staging loads (land during MFMA phase)
        const int cn = (c0 + 64) & 511;
#pragma unroll
        for (int i = 0; i < 7; i++) {
            bf16x8 v;
            if (ok[i]) {
                v = *(const bf16x8*)(Yb + (size_t)gidx[i] * 512 + cn + seg[i] * 8);
            } else {
#pragma unroll
                for (int e = 0; e < 8; e++) v[e] = (bf16_t)0.f;
            }
            vals[i] = v;
        }

#pragma unroll
        for (int t9 = 0; t9 < 9; t9++) {
            const int dy = t9 / 3, dx = t9 % 3;
            // prefetch tap t9+3's A (wraps into next chunk at t9>=6)
            const int nt = t9 + 3;
            const int pc = (nt >= 9) ? cn : c0;
            const int pt = (nt >= 9) ? nt - 9 : nt;
#pragma unroll
            for (int h = 0; h < 2; h++) {
                af3[h][0] = *(const bf16x8*)(Arow[h] + pt * 512 + pc);
                af3[h][1] = *(const bf16x8*)(Arow[h] + pt * 512 + pc + 32);
            }
#pragma unroll
            for (int ns = 0; ns < 4; ns++) {
                int p = dy * 66 + ns * 16 + l16 + dx;
                bf16x8 b0 = *(const bf16x8*)&kTn[p][quad * 8];
                bf16x8 b1 = *(const bf16x8*)&kTn[p][32 + quad * 8];
#pragma unroll
                for (int h = 0; h < 2; h++) {
                    acc[h][ns] = mfma_bf16(af0[h][0], b0, acc[h][ns]);
                    acc[h][ns] = mfma_bf16(af0[h][1], b1, acc[h][ns]);
                }
            }
            // rotate (fully unrolled -> register renaming, no moves)
#pragma unroll
            for (int h = 0; h < 2; h++) {
                af0[h][0] = af1[h][0]; af0[h][1] = af1[h][1];
                af1[h][0] = af2[h][0]; af1[h][1] = af2[h][1];
                af2[h][0] = af3[h][0]; af2[h][1] = af3[h][1];
            }
        }
    }

#pragma unroll
    for (int ms = 0; ms < 2; ms++) {
#pragma unroll
        for (int ns = 0; ns < 4; ns++) {
#pragma unroll
            for (int rr = 0; rr < 4; rr++) {
                int m = mb * 128 + w * 32 + ms * 16 + quad * 4 + rr;
                int x = ns * 16 + l16;
                float v = acc[ms][ns][rr] + bias[m];
                v = v > 0.f ? v : 0.f;
                outp[(size_t)n * strideN + (size_t)m * HW + y * 64 + x] = (bf16_t)v;
            }
        }
    }
}

// ---------------------------------------------------------------------------
// Attention pass B v10 (R16-proven producer-consumer):
// out[c,j] = (sum_i V'[c,i]*exp2(S2[i,j]))/Z[j] + feat,  S2 = log2e*S.
// 512-thr, 8 waves; block = (z, jb 64 j), cb MERGED (S computed once).
// Waves 0-3 produce S->exp2->PT; waves 4-7 consume (64 c-rows, 32 PV-MFMA).
// One barrier/it; PT[2] dbuf race proof as R11.
// ---------------------------------------------------------------------------
#define PSTEP(P, ASC, ASN, ITN)                                                \
    {                                                                          \
        _Pragma("unroll")                                                      \
        for (int ns = 0; ns < 4; ns++) {                                       \
            f32x4 s = mfma_bf16(ASC, bS[ns], zero);                            \
            union { bf16_t h[4]; unsigned long long u; } pk;                   \
            float zs = 0.f;                                                    \
            _Pragma("unroll")                                                  \
            for (int rr = 0; rr < 4; rr++) {                                   \
                pk.h[rr] = (bf16_t)__builtin_amdgcn_exp2f(s[rr]);              \
                zs += (float)pk.h[rr];                                         \
            }                                                                  \
            zacc[ns] += zs;                                                    \
            *(unsigned long long*)&PT[P][ns * 16 + l16][w * 16 + quad * 4] = pk.u; \
        }                                                                      \
        ASN = *(const bf16x8*)(Qa + (size_t)((ITN) & 63) * (64 * 64));         \
        asm volatile("s_waitcnt lgkmcnt(0)" ::: "memory");                     \
        __builtin_amdgcn_s_barrier();                                          \
        __builtin_amdgcn_sched_barrier(0);                                     \
    }

#define CSTEP(P, AVC, AVN, ITN)                                                \
    {                                                                          \
        __builtin_amdgcn_s_barrier();                                          \
        __builtin_amdgcn_sched_barrier(0);                                     \
        __builtin_amdgcn_s_setprio(1);                                         \
        _Pragma("unroll")                                                      \
        for (int ns = 0; ns < 4; ns++) {                                       \
            bf16x8 b0 = *(const bf16x8*)&PT[P][ns * 16 + l16][quad * 8];       \
            bf16x8 b1 = *(const bf16x8*)&PT[P][ns * 16 + l16][32 + quad * 8];  \
            _Pragma("unroll")                                                  \
            for (int ct = 0; ct < 4; ct++) {                                   \
                acc[ct][ns] = mfma_bf16(AVC[ct][0], b0, acc[ct][ns]);          \
                acc[ct][ns] = mfma_bf16(AVC[ct][1], b1, acc[ct][ns]);          \
            }                                                                  \
        }                                                                      \
        __builtin_amdgcn_s_setprio(0);                                         \
        _Pragma("unroll")                                                      \
        for (int ct = 0; ct < 4; ct++) {                                       \
            AVN[ct][0] = *(const bf16x8*)(Vr[ct] + ((ITN) & 63) * 64);         \
            AVN[ct][1] = *(const bf16x8*)(Vr[ct] + ((ITN) & 63) * 64 + 32);    \
        }                                                                      \
        asm volatile("s_waitcnt lgkmcnt(0)" ::: "memory");                     \
        __builtin_amdgcn_sched_barrier(0);                                     \
    }

__global__ __launch_bounds__(512) void attn3_k(const bf16_t* __restrict__ QKT,
                                               const bf16_t* __restrict__ V,
                                               const float* __restrict__ rgb_feat,
                                               const float* __restrict__ chm_feat,
                                               bf16_t* __restrict__ CAT) {
    __shared__ bf16_t PT[2][64][72];  // [buf][j_local][i_local]
    __shared__ float Zp[4][64];
    const int t = threadIdx.x;
    const int lin = blockIdx.x;                       // 0..255
    const int z = (lin >> 1) & 3;                     // XCD-pinned
    const int jb = ((lin >> 3) << 1) | (lin & 1);     // bijective, 0..63
    const int w = t >> 6, lane = t & 63, quad = lane >> 4, l16 = lane & 15;
    const int qs = z ^ 2, n = z & 1;

    const bf16_t* Q = QKT + (size_t)qs * HW * 64;
    f32x4 zero = {0.f, 0.f, 0.f, 0.f};

    if (w < 4) {
        // ================= PRODUCER (waves 0-3) ============================
        bf16x8 bS[4];
#pragma unroll
        for (int ns = 0; ns < 4; ns++)
            bS[ns] = *(const bf16x8*)(Q + (size_t)(jb * 64 + ns * 16 + l16) * 64 + 32 + quad * 8);
        float zacc[4] = {0.f, 0.f, 0.f, 0.f};
        const bf16_t* Qa = Q + (size_t)(w * 16 + l16) * 64 + quad * 8;

        bf16x8 aSa, aSb;
        aSa = *(const bf16x8*)Qa;

        for (int ii = 0; ii < 32; ii++) {
            PSTEP(0, aSa, aSb, 2 * ii + 1);
            PSTEP(1, aSb, aSa, 2 * ii + 2);
        }

        // Z reduce: quads via shuffle, publish per-wave partials
#pragma unroll
        for (int ns = 0; ns < 4; ns++) {
            zacc[ns] += __shfl_xor(zacc[ns], 16, 64);
            zacc[ns] += __shfl_xor(zacc[ns], 32, 64);
        }
        if (lane < 16) {
#pragma unroll
            for (int ns = 0; ns < 4; ns++) Zp[w][ns * 16 + lane] = zacc[ns];
        }
        __syncthreads();
        // producers done
    } else {
        // ================= CONSUMER (waves 4-7) ============================
        const int wc = w - 4;                 // c-quarter: 64 rows
        f32x4 acc[4][4];
#pragma unroll
        for (int i = 0; i < 4; i++)
#pragma unroll
            for (int j = 0; j < 4; j++) acc[i][j] = zero;

        const bf16_t* Vr[4];
#pragma unroll
        for (int ct = 0; ct < 4; ct++)
            Vr[ct] = V + ((size_t)z * 256 + wc * 64 + ct * 16 + l16) * HW + quad * 8;

        bf16x8 aVa[4][2], aVb[4][2];
#pragma unroll
        for (int ct = 0; ct < 4; ct++) {
            aVa[ct][0] = *(const bf16x8*)(Vr[ct]);
            aVa[ct][1] = *(const bf16x8*)(Vr[ct] + 32);
        }

        for (int ii = 0; ii < 32; ii++) {
            CSTEP(0, aVa, aVb, 2 * ii + 1);
            CSTEP(1, aVb, aVa, 2 * ii + 2);
        }

        __syncthreads();  // Zp ready

        float rz[4];
#pragma unroll
        for (int ns = 0; ns < 4; ns++) {
            float ssum = 0.f;
#pragma unroll
            for (int ww = 0; ww < 4; ww++) ssum += Zp[ww][ns * 16 + l16];
            rz[ns] = 1.f / ssum;
        }

        const float* feat = ((z < 2) ? rgb_feat : chm_feat) + (size_t)n * 256 * HW;
        bf16_t* outp = CAT + (size_t)n * 512 * HW + (size_t)(z < 2 ? 0 : 256) * HW;
#pragma unroll
        for (int ct = 0; ct < 4; ct++) {
#pragma unroll
            for (int ns = 0; ns < 4; ns++) {
#pragma unroll
                for (int rr = 0; rr < 4; rr++) {
                    int c = wc * 64 + ct * 16 + quad * 4 + rr;
                    int col = jb * 64 + ns * 16 + l16;
                    float v = acc[ct][ns][rr] * rz[ns] + feat[(size_t)c * HW + col];
                    outp[(size_t)c * HW + col] = (bf16_t)v;
                }
            }
        }
    }
}

// ---------------------------------------------------------------------------
extern "C" void kernel_launch(void* const* d_in, const int* in_sizes, int n_in,
                              void* d_out, int out_size, void* d_ws, size_t ws_size,
                              hipStream_t stream) {
    (void)in_sizes; (void)n_in; (void)out_size; (void)ws_size;

    const float* rgb_feat  = (const float*)d_in[0];
    const float* chm_feat  = (const float*)d_in[1];
    const float* rgb_q_w   = (const float*)d_in[2];
    const float* rgb_q_b   = (const float*)d_in[3];
    const float* rgb_k_w   = (const float*)d_in[4];
    const float* rgb_k_b   = (const float*)d_in[5];
    const float* rgb_v_w   = (const float*)d_in[6];
    const float* rgb_v_b   = (const float*)d_in[7];
    const float* depth_q_w = (const float*)d_in[8];
    const float* depth_q_b = (const float*)d_in[9];
    const float* depth_k_w = (const float*)d_in[10];
    const float* depth_k_b = (const float*)d_in[11];
    const float* depth_v_w = (const float*)d_in[12];
    const float* depth_v_b = (const float*)d_in[13];
    const float* gate_w    = (const float*)d_in[14];
    const float* gate_b    = (const float*)d_in[15];
    const float* fus1_w    = (const float*)d_in[16];
    const float* fus1_b    = (const float*)d_in[17];
    const float* fus2_w    = (const float*)d_in[18];
    const float* fus2_b    = (const float*)d_in[19];
    const float* fus3_w    = (const float*)d_in[20];
    const float* fus3_b    = (const float*)d_in[21];
    const float* skip_w    = (const float*)d_in[22];
    const float* skip_b    = (const float*)d_in[23];

    char* ws = (char*)d_ws;
    size_t off = 0;
    auto alloc = [&](size_t bytes) -> char* {
        char* p = ws + off;
        off += (bytes + 255) & ~(size_t)255;
        return p;
    };

    bf16_t* WQK_R = (bf16_t*)alloc(64 * 256 * 2);
    bf16_t* WQK_D = (bf16_t*)alloc(64 * 256 * 2);
    bf16_t* WV_R  = (bf16_t*)alloc(256 * 256 * 2);
    bf16_t* WV_D  = (bf16_t*)alloc(256 * 256 * 2);
    bf16_t* WGATE = (bf16_t*)alloc(256 * 512 * 2);
    bf16_t* WFUS1 = (bf16_t*)alloc(512 * 512 * 2);
    bf16_t* WFUS2 = (bf16_t*)alloc(512 * 4608 * 2);
    bf16_t* WCAT  = (bf16_t*)alloc(256 * 1024 * 2);      // [skip_w | fus3_w]
    float*  BQK_R = (float*)alloc(64 * 4);
    float*  BQK_D = (float*)alloc(64 * 4);
    float*  BSUM  = (float*)alloc(256 * 4);
    bf16_t* XB    = (bf16_t*)alloc((size_t)4 * 256 * HW * 2);    // [XR n0,n1; XC n0,n1]
    bf16_t* QKT   = (bf16_t*)alloc((size_t)4 * HW * 64 * 2);     // [z][pixel][64]
    bf16_t* V4    = (bf16_t*)alloc((size_t)4 * 256 * HW * 2);    // CHW [z][c][pixel]
    bf16_t* CAT   = (bf16_t*)alloc((size_t)NB * 512 * HW * 2);
    bf16_t* FY    = (bf16_t*)alloc((size_t)NB * 1024 * HW * 2);  // [F ; Y2] NCHW
    bf16_t* Y1    = (bf16_t*)alloc((size_t)NB * HW * 512 * 2);   // NHWC [n][pix][512]

    bf16_t* XR = XB;
    bf16_t* XC = XB + (size_t)2 * 256 * HW;

    // ---- prep: convert + reorder + bias pack, ONE launch -------------------
    CvtJobs J;
    int cum = 0, nj = 0;
    auto addjob = [&](const float* s, bf16_t* d, int cnt, int rl, int rs, int ro) {
        J.src[nj] = s; J.dst[nj] = d; cum += cnt / 8; J.vend[nj] = cum;
        J.rowlen[nj] = rl; J.rowstride[nj] = rs; J.rowoff[nj] = ro; nj++;
    };
    addjob(rgb_feat, XR, NB * 256 * HW, 0, 0, 0);
    addjob(chm_feat, XC, NB * 256 * HW, 0, 0, 0);
    addjob(rgb_q_w, WQK_R, 32 * 256, 0, 0, 0);
    addjob(rgb_k_w, WQK_R + 32 * 256, 32 * 256, 0, 0, 0);
    addjob(depth_q_w, WQK_D, 32 * 256, 0, 0, 0);
    addjob(depth_k_w, WQK_D + 32 * 256, 32 * 256, 0, 0, 0);
    addjob(rgb_v_w, WV_R, 256 * 256, 0, 0, 0);
    addjob(depth_v_w, WV_D, 256 * 256, 0, 0, 0);
    addjob(gate_w, WGATE, 256 * 512, 0, 0, 0);
    addjob(fus1_w, WFUS1, 512 * 512, 0, 0, 0);
    addjob(skip_w, WCAT, 256 * 512, 512, 1024, 0);
    addjob(fus3_w, WCAT, 256 * 512, 512, 1024, 512);
    int totalvec = cum;
    int cvtBlocks = (totalvec + 255) / 256;
    int prepBlocks = cvtBlocks + 9216 + 1;
    prep_k<<<dim3(prepBlocks), 256, 0, stream>>>(
        J, totalvec, cvtBlocks, fus2_w, WFUS2,
        rgb_q_b, rgb_k_b, depth_q_b, depth_k_b, skip_b, fus3_b,
        BQK_R, BQK_D, BSUM);

    // ---- merged V-proj + QKT, ONE launch -----------------------------------
    proj_k<<<dim3(640), 512, 0, stream>>>(
        WV_R, WV_D, WQK_R, WQK_D, XB, rgb_v_b, depth_v_b, BQK_R, BQK_D, V4, QKT);

    // ---- attention pass B + Z + residual -> CAT=[br;bd] NCHW ---------------
    attn3_k<<<dim3(256), 512, 0, stream>>>(QKT, V4, rgb_feat, chm_feat, CAT);

    // ---- gate + gated fusion fused epilogue -> FY rows 0..511 --------------
    gemm_k<5, true><<<dim3(2, 64, NB), 512, 0, stream>>>(
        WGATE, WGATE, CAT, gate_b, gate_b, FY, CAT, 256, 512, (size_t)512 * HW, 0);

    // ---- fus1 (relu) -> Y1 NHWC --------------------------------------------
    gemm_k<7, true><<<dim3(4, 64, NB), 512, 0, stream>>>(
        WFUS1, WFUS1, FY, fus1_b, fus1_b, Y1, nullptr, 512, 512, (size_t)1024 * HW, 0);

    // ---- fus2 conv3x3 (relu) -> FY rows 512..1023 (XCD-pinned 1D grid) ----
    conv3_k<<<dim3(512), 256, 0, stream>>>(WFUS2, Y1, fus2_b,
                                           FY + (size_t)512 * HW, (size_t)1024 * HW);

    // ---- merged skip+fus3: d_out = [skip_w|fus3_w] . [F;Y2] + (skip_b+fus3_b)
    gemm_k<0, false><<<dim3(2, 64, NB), 512, 0, stream>>>(
        WCAT, WCAT, FY, BSUM, BSUM, d_out, nullptr, 256, 1024, (size_t)1024 * HW, (size_t)256 * HW);
}

// Round 15
// 327.261 us; speedup vs baseline: 1.0113x; 1.0113x over previous
//
#include <hip/hip_runtime.h>
#include <stdint.h>

// ---------------------------------------------------------------------------
// GC_FFM fusion block on MI355X (gfx950), bf16 MFMA pipeline.
// N=2, C=256, RC=32, H=W=64, HW=4096.
// R21 = exact R19 (verified session best, 328.1us). R20's depth-3 conv3
// rotation regressed (79.5->83.1: extra moves/pressure; depth-2 optimal)
// and gemm/proj A-prefetch was neutral. Final lock-in.
// Session ladder: 389 -> 328.1 (-15.7%). Bracketed: occupancy (thin/fat
// both lose), sync (LDS-only barriers + producer-consumer win), locality
// (XCD pinning -55% FETCH), prefetch (depth-2 optimal), launches (10->7).
// ---------------------------------------------------------------------------

typedef __bf16 bf16_t;
typedef __bf16 bf16x8 __attribute__((ext_vector_type(8)));
typedef float f32x4 __attribute__((ext_vector_type(4)));

#define HW 4096
#define NB 2

__device__ inline f32x4 mfma_bf16(bf16x8 a, bf16x8 b, f32x4 c) {
    return __builtin_amdgcn_mfma_f32_16x16x32_bf16(a, b, c, 0, 0, 0);
}

// LDS-only barrier: drain LDS ops, sync, pin schedule. Global loads stay
// in flight across it (R11-proven race-free for write->read->overwrite).
#define LBAR()                                                                 \
    do {                                                                       \
        asm volatile("s_waitcnt lgkmcnt(0)" ::: "memory");                     \
        __builtin_amdgcn_s_barrier();                                          \
        __builtin_amdgcn_sched_barrier(0);                                     \
    } while (0)

// ---------------------------------------------------------------------------
// prep_k: batched fp32->bf16 convert + fus2 reorder + bias pack, one launch.
// ---------------------------------------------------------------------------
#define MAXJOB 12
struct CvtJobs {
    const float* src[MAXJOB];
    bf16_t* dst[MAXJOB];
    int vend[MAXJOB];     // cumulative end, vec8 units
    int rowlen[MAXJOB];
    int rowstride[MAXJOB];
    int rowoff[MAXJOB];
};

__global__ __launch_bounds__(256) void prep_k(CvtJobs J, int totalvec, int cvtBlocks,
                                              const float* __restrict__ fus2_src,
                                              bf16_t* __restrict__ fus2_dst,
                                              const float* qr, const float* kr,
                                              const float* qd, const float* kd,
                                              const float* sb, const float* fb,
                                              float* BQK_R, float* BQK_D, float* BSUM) {
    const int b = blockIdx.x, t = threadIdx.x;
    if (b < cvtBlocks) {
        int gv = b * 256 + t;
        if (gv >= totalvec) return;
        int j = 0;
        while (gv >= J.vend[j]) j++;
        int vbase = (j == 0) ? 0 : J.vend[j - 1];
        int e = (gv - vbase) * 8;
        const float* s = J.src[j] + e;
        float4 f0 = *(const float4*)s;
        float4 f1 = *(const float4*)(s + 4);
        bf16x8 o;
        o[0] = (bf16_t)f0.x; o[1] = (bf16_t)f0.y; o[2] = (bf16_t)f0.z; o[3] = (bf16_t)f0.w;
        o[4] = (bf16_t)f1.x; o[5] = (bf16_t)f1.y; o[6] = (bf16_t)f1.z; o[7] = (bf16_t)f1.w;
        int di = e;
        if (J.rowlen[j])
            di = (e / J.rowlen[j]) * J.rowstride[j] + J.rowoff[j] + (e % J.rowlen[j]);
        *(bf16x8*)(J.dst[j] + di) = o;
    } else if (b < cvtBlocks + 9216) {
        // fus2_w [O=512][C=512][3][3] -> A'[o][ (dy*3+dx)*512 + c ]
        int idx = (b - cvtBlocks) * 256 + t;
        int o = idx / 4608;
        int tt = idx % 4608;
        int t9 = tt / 512;
        int c  = tt % 512;
        fus2_dst[idx] = (bf16_t)fus2_src[(size_t)o * 4608 + c * 9 + t9];
    } else {
        if (t < 32) {
            BQK_R[t] = qr[t]; BQK_R[32 + t] = kr[t];
            BQK_D[t] = qd[t]; BQK_D[32 + t] = kd[t];
        }
        BSUM[t] = sb[t] + fb[t];
    }
}

// ---------------------------------------------------------------------------
// proj_k: V-proj (blocks 0..511) + QKT (blocks 512..639), 512 threads.
// ---------------------------------------------------------------------------
__global__ __launch_bounds__(512) void proj_k(const bf16_t* __restrict__ WV_R,
                                              const bf16_t* __restrict__ WV_D,
                                              const bf16_t* __restrict__ WQK_R,
                                              const bf16_t* __restrict__ WQK_D,
                                              const bf16_t* __restrict__ XB,
                                              const float* __restrict__ vb_r,
                                              const float* __restrict__ vb_d,
                                              const float* __restrict__ bqk_r,
                                              const float* __restrict__ bqk_d,
                                              bf16_t* __restrict__ V4,
                                              bf16_t* __restrict__ QKT) {
    __shared__ bf16_t Bt[2][64][72];
    const int t = threadIdx.x, b = blockIdx.x;
    const int w = t >> 6, lane = t & 63, quad = lane >> 4, l16 = lane & 15;

    f32x4 zero = {0.f, 0.f, 0.f, 0.f};
    f32x4 acc[4] = {zero, zero, zero, zero};

    if (b < 512) {
        // ---- V-proj role (NW8) --------------------------------------------
        const int mb = b & 1, jb = (b >> 1) & 63, n = b >> 7;
        const bf16_t* Au = (n >= 2) ? WV_D : WV_R;
        const float* biasu = (n >= 2) ? vb_d : vb_r;
        const bf16_t* Bb = XB + (size_t)n * (256 * HW) + jb * 64;
        const bf16_t* Arow = Au + (size_t)(mb * 128 + w * 16 + l16) * 256 + quad * 8;

        bf16x8 v0 = *(const bf16x8*)(Bb + (size_t)lane * HW + w * 8);
        for (int k0 = 0; k0 < 256; k0 += 64) {
            LBAR();  // prev readers done
#pragma unroll
            for (int e = 0; e < 8; e++) Bt[0][w * 8 + e][lane] = v0[e];
            LBAR();  // tile ready
            const int kn = (k0 + 64 < 256) ? k0 + 64 : 0;
            bf16x8 vp = *(const bf16x8*)(Bb + (size_t)(kn + lane) * HW + w * 8);
            bf16x8 a0 = *(const bf16x8*)(Arow + k0);
            bf16x8 a1 = *(const bf16x8*)(Arow + k0 + 32);
#pragma unroll
            for (int ns = 0; ns < 4; ns++) {
                bf16x8 b0 = *(const bf16x8*)&Bt[0][ns * 16 + l16][quad * 8];
                bf16x8 b1 = *(const bf16x8*)&Bt[0][ns * 16 + l16][32 + quad * 8];
                acc[ns] = mfma_bf16(a0, b0, acc[ns]);
                acc[ns] = mfma_bf16(a1, b1, acc[ns]);
            }
            v0 = vp;
        }
#pragma unroll
        for (int ns = 0; ns < 4; ns++) {
#pragma unroll
            for (int rr = 0; rr < 4; rr++) {
                int m = mb * 128 + w * 16 + quad * 4 + rr;
                int col = jb * 64 + ns * 16 + l16;
                V4[(size_t)n * 256 * HW + (size_t)m * HW + col] =
                    (bf16_t)(acc[ns][rr] + biasu[m]);
            }
        }
    } else {
        // ---- QKT role: two 4-wave groups ----------------------------------
        const int qb = b - 512;                  // 0..127
        const int n2 = qb >> 5, jpair = qb & 31;
        const int g = w >> 2, wg = w & 3;
        const int jb = jpair * 2 + g;
        const bf16_t* Au = (n2 >= 2) ? WQK_D : WQK_R;
        const float* biasu = (n2 >= 2) ? bqk_d : bqk_r;
        const bf16_t* Bb = XB + (size_t)n2 * (256 * HW) + jb * 64;
        const bf16_t* Arow = Au + (size_t)(wg * 16 + l16) * 256 + quad * 8;

        bf16x8 v0 = *(const bf16x8*)(Bb + (size_t)lane * HW + wg * 16);
        bf16x8 v1 = *(const bf16x8*)(Bb + (size_t)lane * HW + wg * 16 + 8);
        for (int k0 = 0; k0 < 256; k0 += 64) {
            LBAR();  // prev readers done
#pragma unroll
            for (int e = 0; e < 8; e++) Bt[g][wg * 16 + e][lane] = v0[e];
#pragma unroll
            for (int e = 0; e < 8; e++) Bt[g][wg * 16 + 8 + e][lane] = v1[e];
            LBAR();  // tile ready
            const int kn = (k0 + 64 < 256) ? k0 + 64 : 0;
            bf16x8 p0 = *(const bf16x8*)(Bb + (size_t)(kn + lane) * HW + wg * 16);
            bf16x8 p1 = *(const bf16x8*)(Bb + (size_t)(kn + lane) * HW + wg * 16 + 8);
            bf16x8 a0 = *(const bf16x8*)(Arow + k0);
            bf16x8 a1 = *(const bf16x8*)(Arow + k0 + 32);
#pragma unroll
            for (int ns = 0; ns < 4; ns++) {
                bf16x8 b0 = *(const bf16x8*)&Bt[g][ns * 16 + l16][quad * 8];
                bf16x8 b1 = *(const bf16x8*)&Bt[g][ns * 16 + l16][32 + quad * 8];
                acc[ns] = mfma_bf16(a0, b0, acc[ns]);
                acc[ns] = mfma_bf16(a1, b1, acc[ns]);
            }
            v0 = p0; v1 = p1;
        }
        // EPI6: transposed store, q-rows (wg<2) pre-scaled by log2e
        const float scl = (wg < 2) ? 1.44269504f : 1.0f;
#pragma unroll
        for (int ns = 0; ns < 4; ns++) {
            int col = jb * 64 + ns * 16 + l16;
            union { bf16_t h[4]; unsigned long long u; } pk;
#pragma unroll
            for (int rr = 0; rr < 4; rr++) {
                int m = wg * 16 + quad * 4 + rr;
                pk.h[rr] = (bf16_t)((acc[ns][rr] + biasu[m]) * scl);
            }
            *(unsigned long long*)(QKT +
                ((size_t)n2 * HW + col) * 64 + wg * 16 + quad * 4) = pk.u;
        }
    }
}

// ---------------------------------------------------------------------------
// Generic bf16 GEMM (NW=8): out = epi( A[z] . B[z] + bias ), dual-A.
// LDS-only barriers + 1-chunk-ahead B prefetch.
// EPI: 0 none (fp32 or bf16), 5 gate-fuse, 7 NHWC transposed relu store.
// ---------------------------------------------------------------------------
template <int EPI, bool OUT_BF16>
__global__ __launch_bounds__(512) void gemm_k(const bf16_t* __restrict__ A,
                                              const bf16_t* __restrict__ A2,
                                              const bf16_t* __restrict__ B,
                                              const float* __restrict__ bias,
                                              const float* __restrict__ bias2,
                                              void* __restrict__ outp,
                                              const void* __restrict__ aux,
                                              int M, int K, size_t strideB, size_t strideO) {
    __shared__ bf16_t Bt[64][72];
    const int t = threadIdx.x;
    const int mb = blockIdx.x, jb = blockIdx.y, n = blockIdx.z;
    const int w = t >> 6, lane = t & 63, quad = lane >> 4, l16 = lane & 15;

    const bf16_t* Au = (n >= 2) ? A2 : A;
    const float* biasu = (n >= 2) ? bias2 : bias;

    const bf16_t* Bb = B + (size_t)n * strideB + jb * 64;

    f32x4 zero = {0.f, 0.f, 0.f, 0.f};
    f32x4 acc[4] = {zero, zero, zero, zero};

    const bf16_t* Arow = Au + (size_t)(mb * 128 + w * 16 + l16) * K + quad * 8;

    bf16x8 v0 = *(const bf16x8*)(Bb + (size_t)lane * HW + w * 8);
    for (int k0 = 0; k0 < K; k0 += 64) {
        LBAR();  // prev readers done (global loads stay in flight)
#pragma unroll
        for (int e = 0; e < 8; e++) Bt[w * 8 + e][lane] = v0[e];
        LBAR();  // tile ready
        const int kn = (k0 + 64 < K) ? k0 + 64 : 0;
        bf16x8 vp = *(const bf16x8*)(Bb + (size_t)(kn + lane) * HW + w * 8);
        bf16x8 a0 = *(const bf16x8*)(Arow + k0);
        bf16x8 a1 = *(const bf16x8*)(Arow + k0 + 32);
#pragma unroll
        for (int ns = 0; ns < 4; ns++) {
            bf16x8 b0 = *(const bf16x8*)&Bt[ns * 16 + l16][quad * 8];
            bf16x8 b1 = *(const bf16x8*)&Bt[ns * 16 + l16][32 + quad * 8];
            acc[ns] = mfma_bf16(a0, b0, acc[ns]);
            acc[ns] = mfma_bf16(a1, b1, acc[ns]);
        }
        v0 = vp;
    }

    if (EPI == 7) {
        // NHWC transposed relu store: Y1[(n*HW + col)*512 + m_base..+4]
        const int m_base = mb * 128 + w * 16 + quad * 4;
#pragma unroll
        for (int ns = 0; ns < 4; ns++) {
            int col = jb * 64 + ns * 16 + l16;
            union { bf16_t h[4]; unsigned long long u; } pk;
#pragma unroll
            for (int rr = 0; rr < 4; rr++) {
                float v = acc[ns][rr] + biasu[m_base + rr];
                pk.h[rr] = (bf16_t)(v > 0.f ? v : 0.f);
            }
            *(unsigned long long*)((bf16_t*)outp +
                ((size_t)n * HW + col) * 512 + m_base) = pk.u;
        }
    } else if (EPI == 5) {
        const bf16_t* catp = (const bf16_t*)aux;
        bf16_t* f = (bf16_t*)outp;
#pragma unroll
        for (int ns = 0; ns < 4; ns++) {
#pragma unroll
            for (int rr = 0; rr < 4; rr++) {
                int m = mb * 128 + w * 16 + quad * 4 + rr;
                int col = jb * 64 + ns * 16 + l16;
                float v = acc[ns][rr] + biasu[m];
                float g = 1.f / (1.f + __expf(-v));
                size_t base = (size_t)n * 512 * HW + (size_t)m * HW + col;
                float br = (float)catp[base];
                float bd = (float)catp[base + (size_t)256 * HW];
                size_t ob = (size_t)n * 1024 * HW + (size_t)m * HW + col;
                f[ob] = (bf16_t)(br * g + bd * (1.f - g));
                f[ob + (size_t)256 * HW] = (bf16_t)(br * bd);
            }
        }
    } else {
#pragma unroll
        for (int ns = 0; ns < 4; ns++) {
#pragma unroll
            for (int rr = 0; rr < 4; rr++) {
                int m = mb * 128 + w * 16 + quad * 4 + rr;
                int col = jb * 64 + ns * 16 + l16;
                float v = acc[ns][rr] + biasu[m];
                size_t oi = (size_t)n * strideO + (size_t)m * HW + col;
                if (OUT_BF16) ((bf16_t*)outp)[oi] = (bf16_t)v;
                else ((float*)outp)[oi] = v;
            }
        }
    }
}

// ---------------------------------------------------------------------------
// conv3x3 implicit GEMM v6 (R19-proven, 79.5us): R16 structure (32m/wave,
// grid 512, 2 blk/CU) + A-tap prefetch 2 taps ahead (3-set rotation;
// R20 proved depth-3 regresses). Prefetch distance ~300cy >= L2 latency.
// ---------------------------------------------------------------------------
__global__ __launch_bounds__(256) void conv3_k(const bf16_t* __restrict__ A,
                                               const bf16_t* __restrict__ Y1n,
                                               const float* __restrict__ bias,
                                               bf16_t* __restrict__ outp,
                                               size_t strideN) {
    __shared__ bf16_t kTn[198][72];  // [px_slot][channel], pad 72 (144B rows)
    const int t = threadIdx.x;
    const int lin = blockIdx.x;
    const int n = lin & 1, mb = (lin >> 1) & 3, y = lin >> 3;
    const int w = t >> 6, lane = t & 63, quad = lane >> 4, l16 = lane & 15;

    f32x4 zero = {0.f, 0.f, 0.f, 0.f};
    f32x4 acc[2][4];
#pragma unroll
    for (int i = 0; i < 2; i++)
#pragma unroll
        for (int j = 0; j < 4; j++) acc[i][j] = zero;

    const bf16_t* Yb = Y1n + (size_t)n * HW * 512;

    const bf16_t* Arow[2];
    Arow[0] = A + (size_t)(mb * 128 + w * 32 + l16) * 4608 + quad * 8;
    Arow[1] = Arow[0] + (size_t)16 * 4608;

    // staging slot geometry: 198 px_slots x 8 ch-segments = 1584 16B units
    int pxs[7], seg[7], gidx[7];
    bool ok[7], act[7];
#pragma unroll
    for (int i = 0; i < 7; i++) {
        int slot = t + i * 256;
        act[i] = slot < 1584;
        int ps = act[i] ? (slot >> 3) : 0;
        pxs[i] = ps;
        seg[i] = slot & 7;
        int r = ps / 66, xm = ps % 66;
        int yy = y + r - 1, xx = xm - 1;
        ok[i] = act[i] && ((unsigned)yy < 64u) && ((unsigned)xx < 64u);
        gidx[i] = ok[i] ? (yy * 64 + xx) : 0;
    }

    bf16x8 vals[7];
    // prologue: chunk 0 staged loads
#pragma unroll
    for (int i = 0; i < 7; i++) {
        bf16x8 v;
        if (ok[i]) {
            v = *(const bf16x8*)(Yb + (size_t)gidx[i] * 512 + seg[i] * 8);
        } else {
#pragma unroll
            for (int e = 0; e < 8; e++) v[e] = (bf16_t)0.f;
        }
        vals[i] = v;
    }

    // prologue: A frags for chunk0 taps 0 and 1 (3-set rotation)
    bf16x8 af0[2][2], af1[2][2], af2[2][2];
#pragma unroll
    for (int h = 0; h < 2; h++) {
        af0[h][0] = *(const bf16x8*)(Arow[h]);
        af0[h][1] = *(const bf16x8*)(Arow[h] + 32);
        af1[h][0] = *(const bf16x8*)(Arow[h] + 512);
        af1[h][1] = *(const bf16x8*)(Arow[h] + 512 + 32);
    }

    for (int c0 = 0; c0 < 512; c0 += 64) {
        LBAR();  // prev chunk's readers done (staged loads stay in flight)
#pragma unroll
        for (int i = 0; i < 7; i++)
            if (act[i]) *(bf16x8*)&kTn[pxs[i]][seg[i] * 8] = vals[i];
        LBAR();  // tile ready

        // prefetch next chunk's staging loads (land during MFMA phase)
        const int cn = (c0 + 64) & 511;
#pragma unroll
        for (int i = 0; i < 7; i++) {
            bf16x8 v;
            if (ok[i]) {
                v = *(const bf16x8*)(Yb + (size_t)gidx[i] * 512 + cn + seg[i] * 8);
            } else {
#pragma unroll
                for (int e = 0; e < 8; e++) v[e] = (bf16_t)0.f;
            }
            vals[i] = v;
        }

#pragma unroll
        for (int t9 = 0; t9 < 9; t9++) {
            const int dy = t9 / 3, dx = t9 % 3;
            // prefetch tap t9+2's A (wraps into next chunk at t9>=7)
            const int nt = t9 + 2;
            const int pc = (nt >= 9) ? cn : c0;
            const int pt = (nt >= 9) ? nt - 9 : nt;
#pragma unroll
            for (int h = 0; h < 2; h++) {
                af2[h][0] = *(const bf16x8*)(Arow[h] + pt * 512 + pc);
                af2[h][1] = *(const bf16x8*)(Arow[h] + pt * 512 + pc + 32);
            }
#pragma unroll
            for (int ns = 0; ns < 4; ns++) {
                int p = dy * 66 + ns * 16 + l16 + dx;
                bf16x8 b0 = *(const bf16x8*)&kTn[p][quad * 8];
                bf16x8 b1 = *(const bf16x8*)&kTn[p][32 + quad * 8];
#pragma unroll
                for (int h = 0; h < 2; h++) {
                    acc[h][ns] = mfma_bf16(af0[h][0], b0, acc[h][ns]);
                    acc[h][ns] = mfma_bf16(af0[h][1], b1, acc[h][ns]);
                }
            }
            // rotate (fully unrolled -> register renaming, no moves)
#pragma unroll
            for (int h = 0; h < 2; h++) {
                af0[h][0] = af1[h][0]; af0[h][1] = af1[h][1];
                af1[h][0] = af2[h][0]; af1[h][1] = af2[h][1];
            }
        }
    }

#pragma unroll
    for (int ms = 0; ms < 2; ms++) {
#pragma unroll
        for (int ns = 0; ns < 4; ns++) {
#pragma unroll
            for (int rr = 0; rr < 4; rr++) {
                int m = mb * 128 + w * 32 + ms * 16 + quad * 4 + rr;
                int x = ns * 16 + l16;
                float v = acc[ms][ns][rr] + bias[m];
                v = v > 0.f ? v : 0.f;
                outp[(size_t)n * strideN + (size_t)m * HW + y * 64 + x] = (bf16_t)v;
            }
        }
    }
}

// ---------------------------------------------------------------------------
// Attention pass B v10 (R16-proven producer-consumer):
// out[c,j] = (sum_i V'[c,i]*exp2(S2[i,j]))/Z[j] + feat,  S2 = log2e*S.
// 512-thr, 8 waves; block = (z, jb 64 j), cb MERGED (S computed once).
// Waves 0-3 produce S->exp2->PT; waves 4-7 consume (64 c-rows, 32 PV-MFMA).
// One barrier/it; PT[2] dbuf race proof as R11.
// ---------------------------------------------------------------------------
#define PSTEP(P, ASC, ASN, ITN)                                                \
    {                                                                          \
        _Pragma("unroll")                                                      \
        for (int ns = 0; ns < 4; ns++) {                                       \
            f32x4 s = mfma_bf16(ASC, bS[ns], zero);                            \
            union { bf16_t h[4]; unsigned long long u; } pk;                   \
            float zs = 0.f;                                                    \
            _Pragma("unroll")                                                  \
            for (int rr = 0; rr < 4; rr++) {                                   \
                pk.h[rr] = (bf16_t)__builtin_amdgcn_exp2f(s[rr]);              \
                zs += (float)pk.h[rr];                                         \
            }                                                                  \
            zacc[ns] += zs;                                                    \
            *(unsigned long long*)&PT[P][ns * 16 + l16][w * 16 + quad * 4] = pk.u; \
        }                                                                      \
        ASN = *(const bf16x8*)(Qa + (size_t)((ITN) & 63) * (64 * 64));         \
        asm volatile("s_waitcnt lgkmcnt(0)" ::: "memory");                     \
        __builtin_amdgcn_s_barrier();                                          \
        __builtin_amdgcn_sched_barrier(0);                                     \
    }

#define CSTEP(P, AVC, AVN, ITN)                                                \
    {                                                                          \
        __builtin_amdgcn_s_barrier();                                          \
        __builtin_amdgcn_sched_barrier(0);                                     \
        __builtin_amdgcn_s_setprio(1);                                         \
        _Pragma("unroll")                                                      \
        for (int ns = 0; ns < 4; ns++) {                                       \
            bf16x8 b0 = *(const bf16x8*)&PT[P][ns * 16 + l16][quad * 8];       \
            bf16x8 b1 = *(const bf16x8*)&PT[P][ns * 16 + l16][32 + quad * 8];  \
            _Pragma("unroll")                                                  \
            for (int ct = 0; ct < 4; ct++) {                                   \
                acc[ct][ns] = mfma_bf16(AVC[ct][0], b0, acc[ct][ns]);          \
                acc[ct][ns] = mfma_bf16(AVC[ct][1], b1, acc[ct][ns]);          \
            }                                                                  \
        }                                                                      \
        __builtin_amdgcn_s_setprio(0);                                         \
        _Pragma("unroll")                                                      \
        for (int ct = 0; ct < 4; ct++) {                                       \
            AVN[ct][0] = *(const bf16x8*)(Vr[ct] + ((ITN) & 63) * 64);         \
            AVN[ct][1] = *(const bf16x8*)(Vr[ct] + ((ITN) & 63) * 64 + 32);    \
        }                                                                      \
        asm volatile("s_waitcnt lgkmcnt(0)" ::: "memory");                     \
        __builtin_amdgcn_sched_barrier(0);                                     \
    }

__global__ __launch_bounds__(512) void attn3_k(const bf16_t* __restrict__ QKT,
                                               const bf16_t* __restrict__ V,
                                               const float* __restrict__ rgb_feat,
                                               const float* __restrict__ chm_feat,
                                               bf16_t* __restrict__ CAT) {
    __shared__ bf16_t PT[2][64][72];  // [buf][j_local][i_local]
    __shared__ float Zp[4][64];
    const int t = threadIdx.x;
    const int lin = blockIdx.x;                       // 0..255
    const int z = (lin >> 1) & 3;                     // XCD-pinned
    const int jb = ((lin >> 3) << 1) | (lin & 1);     // bijective, 0..63
    const int w = t >> 6, lane = t & 63, quad = lane >> 4, l16 = lane & 15;
    const int qs = z ^ 2, n = z & 1;

    const bf16_t* Q = QKT + (size_t)qs * HW * 64;
    f32x4 zero = {0.f, 0.f, 0.f, 0.f};

    if (w < 4) {
        // ================= PRODUCER (waves 0-3) ============================
        bf16x8 bS[4];
#pragma unroll
        for (int ns = 0; ns < 4; ns++)
            bS[ns] = *(const bf16x8*)(Q + (size_t)(jb * 64 + ns * 16 + l16) * 64 + 32 + quad * 8);
        float zacc[4] = {0.f, 0.f, 0.f, 0.f};
        const bf16_t* Qa = Q + (size_t)(w * 16 + l16) * 64 + quad * 8;

        bf16x8 aSa, aSb;
        aSa = *(const bf16x8*)Qa;

        for (int ii = 0; ii < 32; ii++) {
            PSTEP(0, aSa, aSb, 2 * ii + 1);
            PSTEP(1, aSb, aSa, 2 * ii + 2);
        }

        // Z reduce: quads via shuffle, publish per-wave partials
#pragma unroll
        for (int ns = 0; ns < 4; ns++) {
            zacc[ns] += __shfl_xor(zacc[ns], 16, 64);
            zacc[ns] += __shfl_xor(zacc[ns], 32, 64);
        }
        if (lane < 16) {
#pragma unroll
            for (int ns = 0; ns < 4; ns++) Zp[w][ns * 16 + lane] = zacc[ns];
        }
        __syncthreads();
        // producers done
    } else {
        // ================= CONSUMER (waves 4-7) ============================
        const int wc = w - 4;                 // c-quarter: 64 rows
        f32x4 acc[4][4];
#pragma unroll
        for (int i = 0; i < 4; i++)
#pragma unroll
            for (int j = 0; j < 4; j++) acc[i][j] = zero;

        const bf16_t* Vr[4];
#pragma unroll
        for (int ct = 0; ct < 4; ct++)
            Vr[ct] = V + ((size_t)z * 256 + wc * 64 + ct * 16 + l16) * HW + quad * 8;

        bf16x8 aVa[4][2], aVb[4][2];
#pragma unroll
        for (int ct = 0; ct < 4; ct++) {
            aVa[ct][0] = *(const bf16x8*)(Vr[ct]);
            aVa[ct][1] = *(const bf16x8*)(Vr[ct] + 32);
        }

        for (int ii = 0; ii < 32; ii++) {
            CSTEP(0, aVa, aVb, 2 * ii + 1);
            CSTEP(1, aVb, aVa, 2 * ii + 2);
        }

        __syncthreads();  // Zp ready

        float rz[4];
#pragma unroll
        for (int ns = 0; ns < 4; ns++) {
            float ssum = 0.f;
#pragma unroll
            for (int ww = 0; ww < 4; ww++) ssum += Zp[ww][ns * 16 + l16];
            rz[ns] = 1.f / ssum;
        }

        const float* feat = ((z < 2) ? rgb_feat : chm_feat) + (size_t)n * 256 * HW;
        bf16_t* outp = CAT + (size_t)n * 512 * HW + (size_t)(z < 2 ? 0 : 256) * HW;
#pragma unroll
        for (int ct = 0; ct < 4; ct++) {
#pragma unroll
            for (int ns = 0; ns < 4; ns++) {
#pragma unroll
                for (int rr = 0; rr < 4; rr++) {
                    int c = wc * 64 + ct * 16 + quad * 4 + rr;
                    int col = jb * 64 + ns * 16 + l16;
                    float v = acc[ct][ns][rr] * rz[ns] + feat[(size_t)c * HW + col];
                    outp[(size_t)c * HW + col] = (bf16_t)v;
                }
            }
        }
    }
}

// ---------------------------------------------------------------------------
extern "C" void kernel_launch(void* const* d_in, const int* in_sizes, int n_in,
                              void* d_out, int out_size, void* d_ws, size_t ws_size,
                              hipStream_t stream) {
    (void)in_sizes; (void)n_in; (void)out_size; (void)ws_size;

    const float* rgb_feat  = (const float*)d_in[0];
    const float* chm_feat  = (const float*)d_in[1];
    const float* rgb_q_w   = (const float*)d_in[2];
    const float* rgb_q_b   = (const float*)d_in[3];
    const float* rgb_k_w   = (const float*)d_in[4];
    const float* rgb_k_b   = (const float*)d_in[5];
    const float* rgb_v_w   = (const float*)d_in[6];
    const float* rgb_v_b   = (const float*)d_in[7];
    const float* depth_q_w = (const float*)d_in[8];
    const float* depth_q_b = (const float*)d_in[9];
    const float* depth_k_w = (const float*)d_in[10];
    const float* depth_k_b = (const float*)d_in[11];
    const float* depth_v_w = (const float*)d_in[12];
    const float* depth_v_b = (const float*)d_in[13];
    const float* gate_w    = (const float*)d_in[14];
    const float* gate_b    = (const float*)d_in[15];
    const float* fus1_w    = (const float*)d_in[16];
    const float* fus1_b    = (const float*)d_in[17];
    const float* fus2_w    = (const float*)d_in[18];
    const float* fus2_b    = (const float*)d_in[19];
    const float* fus3_w    = (const float*)d_in[20];
    const float* fus3_b    = (const float*)d_in[21];
    const float* skip_w    = (const float*)d_in[22];
    const float* skip_b    = (const float*)d_in[23];

    char* ws = (char*)d_ws;
    size_t off = 0;
    auto alloc = [&](size_t bytes) -> char* {
        char* p = ws + off;
        off += (bytes + 255) & ~(size_t)255;
        return p;
    };

    bf16_t* WQK_R = (bf16_t*)alloc(64 * 256 * 2);
    bf16_t* WQK_D = (bf16_t*)alloc(64 * 256 * 2);
    bf16_t* WV_R  = (bf16_t*)alloc(256 * 256 * 2);
    bf16_t* WV_D  = (bf16_t*)alloc(256 * 256 * 2);
    bf16_t* WGATE = (bf16_t*)alloc(256 * 512 * 2);
    bf16_t* WFUS1 = (bf16_t*)alloc(512 * 512 * 2);
    bf16_t* WFUS2 = (bf16_t*)alloc(512 * 4608 * 2);
    bf16_t* WCAT  = (bf16_t*)alloc(256 * 1024 * 2);      // [skip_w | fus3_w]
    float*  BQK_R = (float*)alloc(64 * 4);
    float*  BQK_D = (float*)alloc(64 * 4);
    float*  BSUM  = (float*)alloc(256 * 4);
    bf16_t* XB    = (bf16_t*)alloc((size_t)4 * 256 * HW * 2);    // [XR n0,n1; XC n0,n1]
    bf16_t* QKT   = (bf16_t*)alloc((size_t)4 * HW * 64 * 2);     // [z][pixel][64]
    bf16_t* V4    = (bf16_t*)alloc((size_t)4 * 256 * HW * 2);    // CHW [z][c][pixel]
    bf16_t* CAT   = (bf16_t*)alloc((size_t)NB * 512 * HW * 2);
    bf16_t* FY    = (bf16_t*)alloc((size_t)NB * 1024 * HW * 2);  // [F ; Y2] NCHW
    bf16_t* Y1    = (bf16_t*)alloc((size_t)NB * HW * 512 * 2);   // NHWC [n][pix][512]

    bf16_t* XR = XB;
    bf16_t* XC = XB + (size_t)2 * 256 * HW;

    // ---- prep: convert + reorder + bias pack, ONE launch -------------------
    CvtJobs J;
    int cum = 0, nj = 0;
    auto addjob = [&](const float* s, bf16_t* d, int cnt, int rl, int rs, int ro) {
        J.src[nj] = s; J.dst[nj] = d; cum += cnt / 8; J.vend[nj] = cum;
        J.rowlen[nj] = rl; J.rowstride[nj] = rs; J.rowoff[nj] = ro; nj++;
    };
    addjob(rgb_feat, XR, NB * 256 * HW, 0, 0, 0);
    addjob(chm_feat, XC, NB * 256 * HW, 0, 0, 0);
    addjob(rgb_q_w, WQK_R, 32 * 256, 0, 0, 0);
    addjob(rgb_k_w, WQK_R + 32 * 256, 32 * 256, 0, 0, 0);
    addjob(depth_q_w, WQK_D, 32 * 256, 0, 0, 0);
    addjob(depth_k_w, WQK_D + 32 * 256, 32 * 256, 0, 0, 0);
    addjob(rgb_v_w, WV_R, 256 * 256, 0, 0, 0);
    addjob(depth_v_w, WV_D, 256 * 256, 0, 0, 0);
    addjob(gate_w, WGATE, 256 * 512, 0, 0, 0);
    addjob(fus1_w, WFUS1, 512 * 512, 0, 0, 0);
    addjob(skip_w, WCAT, 256 * 512, 512, 1024, 0);
    addjob(fus3_w, WCAT, 256 * 512, 512, 1024, 512);
    int totalvec = cum;
    int cvtBlocks = (totalvec + 255) / 256;
    int prepBlocks = cvtBlocks + 9216 + 1;
    prep_k<<<dim3(prepBlocks), 256, 0, stream>>>(
        J, totalvec, cvtBlocks, fus2_w, WFUS2,
        rgb_q_b, rgb_k_b, depth_q_b, depth_k_b, skip_b, fus3_b,
        BQK_R, BQK_D, BSUM);

    // ---- merged V-proj + QKT, ONE launch -----------------------------------
    proj_k<<<dim3(640), 512, 0, stream>>>(
        WV_R, WV_D, WQK_R, WQK_D, XB, rgb_v_b, depth_v_b, BQK_R, BQK_D, V4, QKT);

    // ---- attention pass B + Z + residual -> CAT=[br;bd] NCHW ---------------
    attn3_k<<<dim3(256), 512, 0, stream>>>(QKT, V4, rgb_feat, chm_feat, CAT);

    // ---- gate + gated fusion fused epilogue -> FY rows 0..511 --------------
    gemm_k<5, true><<<dim3(2, 64, NB), 512, 0, stream>>>(
        WGATE, WGATE, CAT, gate_b, gate_b, FY, CAT, 256, 512, (size_t)512 * HW, 0);

    // ---- fus1 (relu) -> Y1 NHWC --------------------------------------------
    gemm_k<7, true><<<dim3(4, 64, NB), 512, 0, stream>>>(
        WFUS1, WFUS1, FY, fus1_b, fus1_b, Y1, nullptr, 512, 512, (size_t)1024 * HW, 0);

    // ---- fus2 conv3x3 (relu) -> FY rows 512..1023 (XCD-pinned 1D grid) ----
    conv3_k<<<dim3(512), 256, 0, stream>>>(WFUS2, Y1, fus2_b,
                                           FY + (size_t)512 * HW, (size_t)1024 * HW);

    // ---- merged skip+fus3: d_out = [skip_w|fus3_w] . [F;Y2] + (skip_b+fus3_b)
    gemm_k<0, false><<<dim3(2, 64, NB), 512, 0, stream>>>(
        WCAT, WCAT, FY, BSUM, BSUM, d_out, nullptr, 256, 1024, (size_t)1024 * HW, (size_t)256 * HW);
}